// Round 12
// baseline (59.023 us; speedup 1.0000x reference)
//
#include <hip/hip_runtime.h>
#include <hip/hip_bf16.h>

// Sinkhorn via MFMA. K = exp(-cost/100) = 1 + E, |E| <= 0.00995.
// Unnormalized chain (row scales cancel in both outputs):
//   v1 = b / S   (S = colsums(K), precomputed -- u0 = 1)
//   u1 = a / (sum_v1 + E v1 + eps)
//   v2 = b / (sum_u1 + E^T u1)
//   u2 = a / (sum_v2 + E v2 + eps);  T = KM v2   (merged phase, KM resident)
//   wnorm = mean sum u2*(T+eps);  grad = centered log(u2) * lam/B
//
// r8 (kept): sched_group_barrier pins pre-RA scheduler -> no fragment-hoist
// spill. r10/r11 (kept): tables precomputed pre-swizzled; coalesced grad
// stores. r12: grid 256 = 1 block/CU, 2 row-tiles/block -- tables staged
// ONCE (E, E^T, KM all LDS-resident, no KM restage barrier); u2+T merged
// into one 64-MFMA phase; tile-1 inputs prefetched under tile-0 compute;
// grad transpose via per-wave TR slices (zero intra-tile barriers).

typedef __attribute__((ext_vector_type(4))) float f32x4;
typedef __attribute__((ext_vector_type(4))) short s16x4;
typedef __attribute__((ext_vector_type(8))) short s16x8;

constexpr int   BLOCK = 512;               // 8 waves, 16 rows each, 2 tiles
constexpr float EPSF  = 1e-8f;
constexpr float LOG2E = 1.44269504088896340736f;
constexpr float LN2   = 0.69314718055994530942f;
constexpr float GRADS = LN2 * 100.0f / 65536.0f;   // ln2 * lam / B

// d_ws layout: halfwords [0:16K) E, [16K:32K) E^T, [32K:48K) KM (swizzled);
// floats: S at f-off 24576 (128 entries), block partials at 24704 (256).

#define SGB_PAIR() do {                                      \
    __builtin_amdgcn_sched_group_barrier(0x100, 2, 0);       \
    __builtin_amdgcn_sched_group_barrier(0x008, 1, 0);       \
  } while (0)
#define SGB_QUAD() do {                                      \
    __builtin_amdgcn_sched_group_barrier(0x100, 4, 0);       \
    __builtin_amdgcn_sched_group_barrier(0x008, 2, 0);       \
  } while (0)

__device__ __forceinline__ unsigned short f2bf(float x) {
  unsigned u = __builtin_bit_cast(unsigned, x);
  u += 0x7fffu + ((u >> 16) & 1u);
  return (unsigned short)(u >> 16);
}
__device__ __forceinline__ float bf2f(short h) {
  return __builtin_bit_cast(float, (unsigned)(unsigned short)h << 16);
}
__device__ __forceinline__ short f2bf_hot(float x) {
  return __builtin_bit_cast(short, __float2bfloat16(x));
}

__device__ __forceinline__ int swzw(int r, int c) {
  return (r << 7) + ((((c >> 2) ^ ((r & 7) << 2)) << 2) | (c & 3));
}

__device__ __forceinline__ s16x8 afrag(const short* M, int row, int kb, int h) {
  const int base = (row << 7) + ((((kb >> 2) + h) ^ ((row & 7) << 2)) << 2);
  const s16x4 lo = *reinterpret_cast<const s16x4*>(M + base);
  const s16x4 hi = *reinterpret_cast<const s16x4*>(M + (base ^ 16));
  s16x8 r;
  r[0] = lo[0]; r[1] = lo[1]; r[2] = lo[2]; r[3] = lo[3];
  r[4] = hi[0]; r[5] = hi[1]; r[6] = hi[2]; r[7] = hi[3];
  return r;
}

__device__ __forceinline__ s16x8 packb(const f32x4 a, const f32x4 b) {
  s16x8 r;
  r[0] = f2bf_hot(a[0]); r[1] = f2bf_hot(a[1]);
  r[2] = f2bf_hot(a[2]); r[3] = f2bf_hot(a[3]);
  r[4] = f2bf_hot(b[0]); r[5] = f2bf_hot(b[1]);
  r[6] = f2bf_hot(b[2]); r[7] = f2bf_hot(b[3]);
  return r;
}

// ---- one-shot precompute: E, E^T, KM (swizzled bf16) + S = colsums(K) ----
__global__ __launch_bounds__(256)
void sink_pre(const float* __restrict__ cost, unsigned short* __restrict__ wh,
              float* __restrict__ Sf)
{
  const float c1 = LOG2E * 0.01f;
  const int tid = threadIdx.x;
  if (blockIdx.x < 32) {
    for (int idx = blockIdx.x * 256 + tid; idx < 16384; idx += 8192) {
      const int r = idx >> 7, c = idx & 127;
      const float cst = cost[idx];
      const float k   = __builtin_amdgcn_exp2f(-cst * c1);
      const unsigned short eb = f2bf(k - 1.0f);
      wh[swzw(r, c)]          = eb;             // E
      wh[16384 + swzw(c, r)]  = eb;             // E^T
      wh[32768 + swzw(r, c)]  = f2bf(cst * k);  // KM
    }
  } else {
    __shared__ float ps[256];
    const int i = tid & 127, jh = tid >> 7;
    float s = 0.f;
#pragma unroll 8
    for (int j = jh * 64; j < jh * 64 + 64; ++j)
      s += __builtin_amdgcn_exp2f(-cost[(j << 7) + i] * c1);
    ps[tid] = s;
    __syncthreads();
    if (tid < 128) Sf[tid] = ps[tid] + ps[tid + 128];
  }
}

__global__ __launch_bounds__(BLOCK, 2)
void sink_mfma(const float* __restrict__ pred,
               const float* __restrict__ tgt,
               const unsigned short* __restrict__ wh,
               const float* __restrict__ Sf,
               float* __restrict__ out,
               float* __restrict__ wsf)
{
  __shared__ __align__(16) short TBL[3 * 16384];  // E | E^T | KM  (96 KB)
  __shared__ __align__(16) float TR[8 * 1024];    // per-wave 4 KB slices

  const short* Es  = TBL;
  const short* ETs = TBL + 16384;
  const short* KMs = TBL + 32768;

  const int tid  = threadIdx.x;
  const int lane = tid & 63;
  const int wv   = tid >> 6;
  const int cl   = lane & 15;
  const int h    = lane >> 4;

  // ---- tile-0 inputs + rcp(S) (latency overlaps staging below)
  const int rr0 = (((blockIdx.x << 8) + (wv << 4) + cl) << 7) + (h << 2);
  float4 p4[8], t4[8], rs[8];
#pragma unroll
  for (int mt = 0; mt < 8; ++mt) {
    p4[mt] = *reinterpret_cast<const float4*>(&pred[rr0 + (mt << 4)]);
    t4[mt] = *reinterpret_cast<const float4*>(&tgt [rr0 + (mt << 4)]);
    const float4 s = *reinterpret_cast<const float4*>(&Sf[(mt << 4) + (h << 2)]);
    rs[mt].x = __builtin_amdgcn_rcpf(s.x);
    rs[mt].y = __builtin_amdgcn_rcpf(s.y);
    rs[mt].z = __builtin_amdgcn_rcpf(s.z);
    rs[mt].w = __builtin_amdgcn_rcpf(s.w);
  }

  // ---- stage all three tables once (pre-swizzled, coalesced)
  {
    const uint4* g = reinterpret_cast<const uint4*>(wh);
    uint4* l = reinterpret_cast<uint4*>(TBL);
#pragma unroll
    for (int k = 0; k < 12; ++k) l[tid + k * BLOCK] = g[tid + k * BLOCK];
  }
  __syncthreads();

  float wacc = 0.f;
  float* TRw = TR + (wv << 10);

#pragma unroll
  for (int tile = 0; tile < 2; ++tile) {
    // ---- pack a,b; v1 = b/S; sum_v1
    s16x8 ab[4], bb[4], vf[4], uf[4];
    f32x4 X[8], T[8];
    float sum_v = 0.f;
#pragma unroll
    for (int mt = 0; mt < 8; ++mt) {
      f32x4 qa, qb, v;
      qa[0] = p4[mt].x + EPSF; qa[1] = p4[mt].y + EPSF;
      qa[2] = p4[mt].z + EPSF; qa[3] = p4[mt].w + EPSF;
      qb[0] = t4[mt].x + EPSF; qb[1] = t4[mt].y + EPSF;
      qb[2] = t4[mt].z + EPSF; qb[3] = t4[mt].w + EPSF;
      v[0] = qb[0] * rs[mt].x; v[1] = qb[1] * rs[mt].y;
      v[2] = qb[2] * rs[mt].z; v[3] = qb[3] * rs[mt].w;
      sum_v += v[0] + v[1] + v[2] + v[3];
      X[mt] = v;
#pragma unroll
      for (int q = 0; q < 4; ++q) {
        ab[mt >> 1][(mt & 1) * 4 + q] = f2bf_hot(qa[q]);
        bb[mt >> 1][(mt & 1) * 4 + q] = f2bf_hot(qb[q]);
      }
    }
#pragma unroll
    for (int s = 0; s < 4; ++s) vf[s] = packb(X[2 * s], X[2 * s + 1]);
    sum_v += __shfl_xor(sum_v, 16);
    sum_v += __shfl_xor(sum_v, 32);

    // ---- prefetch tile-1 inputs under tile-0 compute
    if (tile == 0) {
      const int rr1 = rr0 + (128 << 7);
#pragma unroll
      for (int mt = 0; mt < 8; ++mt) {
        p4[mt] = *reinterpret_cast<const float4*>(&pred[rr1 + (mt << 4)]);
        t4[mt] = *reinterpret_cast<const float4*>(&tgt [rr1 + (mt << 4)]);
      }
    }

    // ======== u1 = a / (sum_v1 + E v1 + eps) ========
#pragma unroll
    for (int mt = 0; mt < 8; ++mt) X[mt] = f32x4{0, 0, 0, 0};
#pragma unroll
    for (int s = 0; s < 4; ++s)
#pragma unroll
      for (int mt = 0; mt < 8; ++mt) {
        X[mt] = __builtin_amdgcn_mfma_f32_16x16x32_bf16(
            afrag(Es, cl + (mt << 4), s << 5, h), vf[s], X[mt], 0, 0, 0);
        SGB_PAIR();
      }
    float sum_u = 0.f;
#pragma unroll
    for (int mt = 0; mt < 8; ++mt)
#pragma unroll
      for (int q = 0; q < 4; ++q) {
        const float a = bf2f(ab[mt >> 1][(mt & 1) * 4 + q]);
        const float r = a * __builtin_amdgcn_rcpf(sum_v + X[mt][q] + EPSF);
        X[mt][q] = r;
        sum_u += r;
      }
#pragma unroll
    for (int s = 0; s < 4; ++s) uf[s] = packb(X[2 * s], X[2 * s + 1]);
    sum_u += __shfl_xor(sum_u, 16);
    sum_u += __shfl_xor(sum_u, 32);

    // ======== v2 = b / (sum_u1 + E^T u1) ========
#pragma unroll
    for (int mt = 0; mt < 8; ++mt) X[mt] = f32x4{0, 0, 0, 0};
#pragma unroll
    for (int s = 0; s < 4; ++s)
#pragma unroll
      for (int mt = 0; mt < 8; ++mt) {
        X[mt] = __builtin_amdgcn_mfma_f32_16x16x32_bf16(
            afrag(ETs, cl + (mt << 4), s << 5, h), uf[s], X[mt], 0, 0, 0);
        SGB_PAIR();
      }
    sum_v = 0.f;
#pragma unroll
    for (int mt = 0; mt < 8; ++mt)
#pragma unroll
      for (int q = 0; q < 4; ++q) {
        const float b = bf2f(bb[mt >> 1][(mt & 1) * 4 + q]);
        const float v = b * __builtin_amdgcn_rcpf(sum_u + X[mt][q]);
        X[mt][q] = v;
        sum_v += v;
      }
#pragma unroll
    for (int s = 0; s < 4; ++s) vf[s] = packb(X[2 * s], X[2 * s + 1]);
    sum_v += __shfl_xor(sum_v, 16);
    sum_v += __shfl_xor(sum_v, 32);

    // ======== merged: u2 = a/(sum_v2 + E v2 + eps) ; T = KM v2 ========
#pragma unroll
    for (int mt = 0; mt < 8; ++mt) {
      X[mt] = f32x4{0, 0, 0, 0};
      T[mt] = f32x4{0, 0, 0, 0};
    }
#pragma unroll
    for (int s = 0; s < 4; ++s)
#pragma unroll
      for (int mt = 0; mt < 8; ++mt) {
        X[mt] = __builtin_amdgcn_mfma_f32_16x16x32_bf16(
            afrag(Es, cl + (mt << 4), s << 5, h), vf[s], X[mt], 0, 0, 0);
        T[mt] = __builtin_amdgcn_mfma_f32_16x16x32_bf16(
            afrag(KMs, cl + (mt << 4), s << 5, h), vf[s], T[mt], 0, 0, 0);
        SGB_QUAD();
      }
#pragma unroll
    for (int mt = 0; mt < 8; ++mt)
#pragma unroll
      for (int q = 0; q < 4; ++q) {
        const float a = bf2f(ab[mt >> 1][(mt & 1) * 4 + q]);
        X[mt][q] = a * __builtin_amdgcn_rcpf(sum_v + X[mt][q] + EPSF);  // u2
      }

    // wnorm partial (per-lane, accumulated across tiles)
#pragma unroll
    for (int mt = 0; mt < 8; ++mt)
#pragma unroll
      for (int q = 0; q < 4; ++q)
        wacc += X[mt][q] * (T[mt][q] + EPSF);

    // ---- grad = (log2(u2) - rowmean)*ln2*lam/B, per-wave transpose, no syncs
    {
#pragma unroll
      for (int mt = 0; mt < 8; ++mt)
#pragma unroll
        for (int q = 0; q < 4; ++q)
          X[mt][q] = __builtin_amdgcn_logf(X[mt][q]);
      float sm = 0.f;
#pragma unroll
      for (int mt = 0; mt < 8; ++mt)
#pragma unroll
        for (int q = 0; q < 4; ++q) sm += X[mt][q];
      sm += __shfl_xor(sm, 16);
      sm += __shfl_xor(sm, 32);
      const float mean = sm * 0.0078125f;

      const int owave = 1 + ((((blockIdx.x << 1) + tile) << 7) + (wv << 4)) * 128;
      const int rloc = cl & 7;
#pragma unroll
      for (int p = 0; p < 2; ++p) {
        if ((cl >> 3) == p) {
#pragma unroll
          for (int mt = 0; mt < 8; ++mt)
#pragma unroll
            for (int q = 0; q < 4; ++q) {
              const int col = (mt << 4) + (h << 2) + q;
              TRw[(rloc << 7) + (col ^ (rloc << 2))] = (X[mt][q] - mean) * GRADS;
            }
        }
#pragma unroll
        for (int k = 0; k < 16; ++k) {
          const int lin = k * 64 + lane;
          const int r = lin >> 7, c = lin & 127;
          out[owave + (p << 10) + lin] = TRw[(r << 7) + (c ^ (r << 2))];
        }
      }
    }
  }

  // ---- wnorm block reduction
  wacc += __shfl_xor(wacc, 1);
  wacc += __shfl_xor(wacc, 2);
  wacc += __shfl_xor(wacc, 4);
  wacc += __shfl_xor(wacc, 8);
  wacc += __shfl_xor(wacc, 16);
  wacc += __shfl_xor(wacc, 32);
  __syncthreads();
  if (lane == 0) TR[wv] = wacc;
  __syncthreads();
  if (tid == 0) {
    float s = 0.f;
#pragma unroll
    for (int w = 0; w < 8; ++w) s += TR[w];
    wsf[blockIdx.x] = s;
  }
}

__global__ void sink_reduce(const float* __restrict__ wsf, float* __restrict__ out)
{
  float s = 0.f;
  for (int i = threadIdx.x; i < 256; i += 256) s += wsf[i];
  s += __shfl_xor(s, 1);
  s += __shfl_xor(s, 2);
  s += __shfl_xor(s, 4);
  s += __shfl_xor(s, 8);
  s += __shfl_xor(s, 16);
  s += __shfl_xor(s, 32);
  __shared__ float sm[4];
  if ((threadIdx.x & 63) == 0) sm[threadIdx.x >> 6] = s;
  __syncthreads();
  if (threadIdx.x == 0) out[0] = (sm[0] + sm[1] + sm[2] + sm[3]) * (1.0f / 65536.0f);
}

extern "C" void kernel_launch(void* const* d_in, const int* in_sizes, int n_in,
                              void* d_out, int out_size, void* d_ws, size_t ws_size,
                              hipStream_t stream)
{
  const float* pred = (const float*)d_in[0];
  const float* tgt  = (const float*)d_in[1];
  const float* cost = (const float*)d_in[2];
  float* out = (float*)d_out;
  unsigned short* wh = (unsigned short*)d_ws;       // 96 KB tables
  float* Sf  = ((float*)d_ws) + 24576;              // 128 colsums
  float* wsf = ((float*)d_ws) + 24704;              // 256 block partials

  sink_pre<<<33, 256, 0, stream>>>(cost, wh, Sf);
  sink_mfma<<<256, BLOCK, 0, stream>>>(pred, tgt, wh, Sf, out, wsf);
  sink_reduce<<<1, 256, 0, stream>>>(wsf, out);
}